// Round 1
// baseline (462.795 us; speedup 1.0000x reference)
//
#include <hip/hip_runtime.h>

// Problem constants: B=4, C=32, D=H=W=64, N(fuzzy)=4
constexpr int Cc = 32;
constexpr int SP = 64 * 64 * 64;   // 262144 spatial per batch
constexpr int TS = 4 * SP;         // 1048576 total spatial

// Workspace layout (floats): [0, TS) fuzz (4 MiB); acc = ws+TS:
//   acc[0..2): bn1 sum,sumsq   acc[2..4): bn1 a,c
//   acc[4..36): bn2 scale      acc[36..68): bn2 shift
//   acc[68..68+4096): bn2 partial sums, idx = 68 + (st*32+c)*64 + slot
constexpr int ACC_N = 68 + 64 * 64;

// ---------------- Kernel 1: conv1 (32->1, 3x3x3 SAME) + fuzzy + bn1 stats
// 1z x 4w register tile (was 2z x 4w): 1024 blocks -> 16 waves/CU instead of 8.
// Double-buffered 9x float4 prefetch of channel c+1 during compute of channel c.
__global__ __launch_bounds__(256) void k_conv1_fuzzy(
    const float* __restrict__ x, const float* __restrict__ w1,
    const float* __restrict__ b1, const float* __restrict__ mu,
    const float* __restrict__ sg, float* __restrict__ fuzz,
    float* __restrict__ acc)
{
    const int tid = threadIdx.x;
    const int t = blockIdx.x * 256 + tid;        // 262144 threads
    const int wq = t & 15;        const int w0 = wq << 2;
    const int z  = (t >> 4) & 63;
    const int y  = (t >> 10) & 63;
    const int b  = t >> 16;
    const int lane = tid & 63;

    float S1 = 0.f, S2 = 0.f, S3 = 0.f;
#pragma unroll
    for (int n = 0; n < 4; n++) {
        float m = mu[n], s = sg[n];
        float iv = 1.0f / (s * s);
        S1 += iv; S2 += m * iv; S3 += m * m * iv;
    }

    const float b1v = b1[0];
    float a0 = b1v, a1 = b1v, a2 = b1v, a3 = b1v;

    const float* xb = x + (size_t)b * Cc * SP;

    // channel-invariant row predicates + offsets (3z x 3y = 9 rows)
    bool pv[9]; int ofs[9];
#pragma unroll
    for (int rz = 0; rz < 3; rz++) {
        const int zz = z - 1 + rz;
        const bool okz = (unsigned)zz < 64u;
#pragma unroll
        for (int dy = 0; dy < 3; dy++) {
            const int yy = y - 1 + dy;
            pv[rz * 3 + dy]  = okz && ((unsigned)yy < 64u);
            ofs[rz * 3 + dy] = (zz << 12) + (yy << 6) + w0;
        }
    }

    auto LOADCH = [&](int c, float4 (&M)[9]) {
        const float* xc = xb + (size_t)c * SP;
#pragma unroll
        for (int i = 0; i < 9; i++)
            M[i] = pv[i] ? *(const float4*)(xc + ofs[i])
                         : make_float4(0.f, 0.f, 0.f, 0.f);
    };

    auto COMPUTECH = [&](int c, const float4 (&M)[9]) {
        const float* wc = w1 + c * 27;           // uniform -> s_load
        float Wv[27];
#pragma unroll
        for (int k = 0; k < 27; k++) Wv[k] = wc[k];
#pragma unroll
        for (int i = 0; i < 9; i++) {
            const float4 m = M[i];
            const float lv = __shfl(m.w, (lane + 63) & 63, 64);
            const float rv = __shfl(m.x, (lane + 1) & 63, 64);
            const float v0 = (wq > 0)  ? lv : 0.f;
            const float v5 = (wq < 15) ? rv : 0.f;
            const float W0 = Wv[i * 3], W1 = Wv[i * 3 + 1], W2 = Wv[i * 3 + 2];
            a0 = fmaf(v0,  W0, fmaf(m.x, W1, fmaf(m.y, W2, a0)));
            a1 = fmaf(m.x, W0, fmaf(m.y, W1, fmaf(m.z, W2, a1)));
            a2 = fmaf(m.y, W0, fmaf(m.z, W1, fmaf(m.w, W2, a2)));
            a3 = fmaf(m.z, W0, fmaf(m.w, W1, fmaf(v5,  W2, a3)));
        }
    };

    float4 Ma[9], Mb[9];
    LOADCH(0, Ma);
    for (int c = 0; c < Cc; c += 2) {
        LOADCH(c + 1, Mb);                 // prefetch while computing c
        COMPUTECH(c, Ma);
        if (c + 2 < Cc) LOADCH(c + 2, Ma); // prefetch while computing c+1
        COMPUTECH(c + 1, Mb);
    }

    // fuzzy + store + bn1 stats
    float fsum = 0.f, fsq = 0.f;
    float xv[4] = { a0, a1, a2, a3 };
    float4 fv; float* fp = &fv.x;
#pragma unroll
    for (int ow = 0; ow < 4; ow++) {
        float x1 = xv[ow];
        float tt = x1 * x1 * S1 - 2.0f * x1 * S2 + S3;
        float fz = __expf(-tt);
        fp[ow] = fz; fsum += fz; fsq += fz * fz;
    }
    *(float4*)(fuzz + (size_t)b * SP + (z << 12) + (y << 6) + w0) = fv;

#pragma unroll
    for (int m = 1; m < 64; m <<= 1) {
        fsum += __shfl_xor(fsum, m, 64);
        fsq  += __shfl_xor(fsq,  m, 64);
    }
    __shared__ float red[8];
    const int wid = tid >> 6;
    if ((tid & 63) == 0) { red[wid * 2] = fsum; red[wid * 2 + 1] = fsq; }
    __syncthreads();
    if (tid == 0) {
        atomicAdd(&acc[0], red[0] + red[2] + red[4] + red[6]);
        atomicAdd(&acc[1], red[1] + red[3] + red[5] + red[7]);
    }
}

// ---------------- Kernel 2: finalize bn1 -> affine (a, c)
__global__ void k_fin1(const float* __restrict__ g, const float* __restrict__ be,
                       float* __restrict__ acc)
{
    float mean = acc[0] * (1.0f / TS);
    float var  = acc[1] * (1.0f / TS) - mean * mean;
    float a = g[0] * rsqrtf(var + 1e-5f);
    acc[2] = a;
    acc[3] = be[0] - mean * a;
}

// ---------------- Kernel 3: conv2 single pass — writes RAW y to out + bn2 stats.
// Each block = one spatial tile (64w x 1y x 4z); each of the 4 waves owns 8
// channels (shorter per-wave reduction chains, 4x more blocks for TLP).
// Raw y is normalized in place later by k_bn2_apply.
__global__ __launch_bounds__(256) void k_conv2_fused(
    const float* __restrict__ fuzz, const float* __restrict__ w2,
    const float* __restrict__ b2, float* __restrict__ acc,
    float* __restrict__ out)
{
    const int tid = threadIdx.x;
    const int lane = tid & 63;
    const int wid = tid >> 6;              // channel group 0..3
    const int bi = blockIdx.x;             // 4096 spatial tiles
    const int w = lane;
    const int y = bi & 63;
    const int z0 = ((bi >> 6) & 15) << 2;
    const int b = bi >> 10;
    const float a = acc[2], sh = acc[3];
    const float* fb = fuzz + (size_t)b * SP;

    float Fl[6][3], Fm[6][3], Fr[6][3];
#pragma unroll
    for (int rz = 0; rz < 6; rz++) {
        const int zz = z0 - 1 + rz;
        const bool okz = (unsigned)zz < 64u;
#pragma unroll
        for (int dy = 0; dy < 3; dy++) {
            const int yy = y - 1 + dy;
            float f = 0.f;
            if (okz && (unsigned)yy < 64u)
                f = fmaf(a, fb[(zz << 12) + (yy << 6) + w], sh);
            const float lv = __shfl(f, (lane + 63) & 63, 64);
            const float rv = __shfl(f, (lane + 1) & 63, 64);
            Fm[rz][dy] = f;
            Fl[rz][dy] = (w > 0)  ? lv : 0.f;
            Fr[rz][dy] = (w < 63) ? rv : 0.f;
        }
    }

    float* ob = out + (size_t)b * Cc * SP + (z0 << 12) + (y << 6) + w;
    const int slot = bi & 63;
    const int c0 = wid * 8;

#pragma unroll
    for (int ci = 0; ci < 8; ci++) {
        const int c = c0 + ci;
        const float* wc = w2 + c * 27;     // uniform -> s_load
        float Wv[27];
#pragma unroll
        for (int k = 0; k < 27; k++) Wv[k] = wc[k];
        const float bb = b2[c];
        float o0 = bb, o1 = bb, o2 = bb, o3 = bb;
#pragma unroll
        for (int rz = 0; rz < 6; rz++) {
#pragma unroll
            for (int dy = 0; dy < 3; dy++) {
                const float l = Fl[rz][dy], m = Fm[rz][dy], r = Fr[rz][dy];
#pragma unroll
                for (int oz = 0; oz < 4; oz++) {
                    const int dz = rz - oz;
                    if (dz < 0 || dz > 2) continue;
                    const float W0 = Wv[(dz*3+dy)*3], W1 = Wv[(dz*3+dy)*3+1], W2 = Wv[(dz*3+dy)*3+2];
                    if      (oz == 0) o0 = fmaf(l, W0, fmaf(m, W1, fmaf(r, W2, o0)));
                    else if (oz == 1) o1 = fmaf(l, W0, fmaf(m, W1, fmaf(r, W2, o1)));
                    else if (oz == 2) o2 = fmaf(l, W0, fmaf(m, W1, fmaf(r, W2, o2)));
                    else              o3 = fmaf(l, W0, fmaf(m, W1, fmaf(r, W2, o3)));
                }
            }
        }
        // write raw y (coalesced 256B per store)
        ob[(size_t)c * SP]         = o0;
        ob[(size_t)c * SP + 4096]  = o1;
        ob[(size_t)c * SP + 8192]  = o2;
        ob[(size_t)c * SP + 12288] = o3;

        float ps = (o0 + o1) + (o2 + o3);
        float pq = fmaf(o0, o0, fmaf(o1, o1, fmaf(o2, o2, o3 * o3)));
#pragma unroll
        for (int mm = 1; mm < 64; mm <<= 1) {
            ps += __shfl_xor(ps, mm, 64);
            pq += __shfl_xor(pq, mm, 64);
        }
        if (lane == 0) {
            atomicAdd(&acc[68 + c * 64 + slot], ps);
            atomicAdd(&acc[68 + (32 + c) * 64 + slot], pq);
        }
    }
}

// ---------------- Kernel 4: finalize bn2 -> per-channel scale/shift
__global__ void k_fin2(const float* __restrict__ g, const float* __restrict__ be,
                       float* __restrict__ acc)
{
    int c = threadIdx.x;                  // 32 threads
    float s = 0.f, q = 0.f;
    for (int k = 0; k < 64; k++) {
        s += acc[68 + c * 64 + k];
        q += acc[68 + (32 + c) * 64 + k];
    }
    float mean = s * (1.0f / TS);
    float var  = q * (1.0f / TS) - mean * mean;
    float sc = g[c] * rsqrtf(var + 1e-5f);
    acc[4 + c]  = sc;
    acc[36 + c] = be[c] - mean * sc;
}

// ---------------- Kernel 5: bn2 affine applied in place (float4 streaming)
__global__ __launch_bounds__(256) void k_bn2_apply(
    const float* __restrict__ acc, float* __restrict__ out)
{
    const int t = blockIdx.x * 256 + threadIdx.x;   // 8388608 threads
    const int c = (t >> 16) & 31;                   // SP/4 = 65536 float4 per (b,c)
    const float sc = acc[4 + c], sh = acc[36 + c];
    float4 v = ((const float4*)out)[t];
    v.x = fmaf(v.x, sc, sh);
    v.y = fmaf(v.y, sc, sh);
    v.z = fmaf(v.z, sc, sh);
    v.w = fmaf(v.w, sc, sh);
    ((float4*)out)[t] = v;
}

extern "C" void kernel_launch(void* const* d_in, const int* in_sizes, int n_in,
                              void* d_out, int out_size, void* d_ws, size_t ws_size,
                              hipStream_t stream)
{
    const float* x   = (const float*)d_in[0];
    const float* w1  = (const float*)d_in[1];
    const float* b1  = (const float*)d_in[2];
    const float* w2  = (const float*)d_in[3];
    const float* b2  = (const float*)d_in[4];
    const float* mu  = (const float*)d_in[5];
    const float* sg  = (const float*)d_in[6];
    const float* g1  = (const float*)d_in[7];
    const float* be1 = (const float*)d_in[8];
    const float* g2  = (const float*)d_in[9];
    const float* be2 = (const float*)d_in[10];

    float* out  = (float*)d_out;
    float* fuzz = (float*)d_ws;
    float* acc  = fuzz + TS;

    hipMemsetAsync(acc, 0, ACC_N * sizeof(float), stream);
    k_conv1_fuzzy<<<1024, 256, 0, stream>>>(x, w1, b1, mu, sg, fuzz, acc);
    k_fin1<<<1, 1, 0, stream>>>(g1, be1, acc);
    k_conv2_fused<<<4096, 256, 0, stream>>>(fuzz, w2, b2, acc, out);
    k_fin2<<<1, 32, 0, stream>>>(g2, be2, acc);
    k_bn2_apply<<<32768, 256, 0, stream>>>(acc, out);
}

// Round 2
// 378.396 us; speedup vs baseline: 1.2230x; 1.2230x over previous
//
#include <hip/hip_runtime.h>

// Problem constants: B=4, C=32, D=H=W=64, N(fuzzy)=4
constexpr int Cc = 32;
constexpr int SP = 64 * 64 * 64;   // 262144 spatial per batch
constexpr int TS = 4 * SP;         // 1048576 total spatial

// Padded fuzz layout: [B][66][66][68] (z,y,w each +1 halo; w +2 extra for pitch)
constexpr int PW  = 68;
constexpr int PZR = 66 * PW;       // 4488 floats per z-slice row-block
constexpr int PSP = 66 * PZR;      // 296208 floats per batch
constexpr int PTOT = 4 * PSP;      // 1184832 floats

// Workspace layout (floats): [0, PTOT) padded fuzz; acc = ws+PTOT:
//   acc[0..2): bn1 sum,sumsq   acc[2..4): bn1 a,c
//   acc[4..36): bn2 scale      acc[36..68): bn2 shift
//   acc[68..68+4096): bn2 partial sums, idx = 68 + (st*32+c)*64 + slot
constexpr int ACC_N = 68 + 64 * 64;

// ---------------- Kernel 1: conv1 (32->1, 3x3x3 SAME) + fuzzy + bn1 stats
// 2z x 4w register tile. BRANCHLESS loads: offsets clamped to valid rows so all
// 12 float4 loads issue unconditionally (clustered, prefetchable); invalid rows
// zeroed by cndmask at the top of the consuming COMPUTECH (one channel of
// latency after issue).
__global__ __launch_bounds__(256) void k_conv1_fuzzy(
    const float* __restrict__ x, const float* __restrict__ w1,
    const float* __restrict__ b1, const float* __restrict__ mu,
    const float* __restrict__ sg, float* __restrict__ fuzz,
    float* __restrict__ acc)
{
    const int tid = threadIdx.x;
    const int t = blockIdx.x * 256 + tid;        // 131072 threads
    const int wq = t & 15;        const int w0 = wq << 2;
    const int zp = (t >> 4) & 31; const int z0 = zp << 1;
    const int y  = (t >> 9) & 63;
    const int b  = t >> 15;
    const int lane = tid & 63;

    float S1 = 0.f, S2 = 0.f, S3 = 0.f;
#pragma unroll
    for (int n = 0; n < 4; n++) {
        float m = mu[n], s = sg[n];
        float iv = 1.0f / (s * s);
        S1 += iv; S2 += m * iv; S3 += m * m * iv;
    }

    const float b1v = b1[0];
    float a00 = b1v, a01 = b1v, a02 = b1v, a03 = b1v;
    float a10 = b1v, a11 = b1v, a12 = b1v, a13 = b1v;

    const float* xb = x + (size_t)b * Cc * SP;

    // channel-invariant row predicates + CLAMPED offsets (always-valid addrs)
    bool pv[12]; int ofs[12];
#pragma unroll
    for (int rz = 0; rz < 4; rz++) {
        const int zz = z0 - 1 + rz;
        const int zzc = min(max(zz, 0), 63);
        const bool okz = (unsigned)zz < 64u;
#pragma unroll
        for (int dy = 0; dy < 3; dy++) {
            const int yy = y - 1 + dy;
            const int yyc = min(max(yy, 0), 63);
            pv[rz * 3 + dy]  = okz && ((unsigned)yy < 64u);
            ofs[rz * 3 + dy] = (zzc << 12) + (yyc << 6) + w0;
        }
    }

    auto LOADCH = [&](int c, float4 (&M)[12]) {
        const float* xc = xb + (size_t)c * SP;
#pragma unroll
        for (int i = 0; i < 12; i++)
            M[i] = *(const float4*)(xc + ofs[i]);   // unconditional, clustered
    };

    auto COMPUTECH = [&](int c, float4 (&M)[12]) {
        // zero invalid rows (vmcnt wait lands here — loads were issued a full
        // channel-compute earlier)
#pragma unroll
        for (int i = 0; i < 12; i++) {
            if (true) {
                M[i].x = pv[i] ? M[i].x : 0.f;
                M[i].y = pv[i] ? M[i].y : 0.f;
                M[i].z = pv[i] ? M[i].z : 0.f;
                M[i].w = pv[i] ? M[i].w : 0.f;
            }
        }
        const float* wc = w1 + c * 27;           // uniform -> s_load
        float Wv[27];
#pragma unroll
        for (int k = 0; k < 27; k++) Wv[k] = wc[k];
#pragma unroll
        for (int rz = 0; rz < 4; rz++) {
#pragma unroll
            for (int dy = 0; dy < 3; dy++) {
                const float4 m = M[rz * 3 + dy];
                const float lv = __shfl(m.w, (lane + 63) & 63, 64);
                const float rv = __shfl(m.x, (lane + 1) & 63, 64);
                const float v0 = (wq > 0)  ? lv : 0.f;
                const float v5 = (wq < 15) ? rv : 0.f;
                const float v1 = m.x, v2 = m.y, v3 = m.z, v4 = m.w;
                if (rz < 3) {
                    const float W0 = Wv[(rz*3+dy)*3], W1 = Wv[(rz*3+dy)*3+1], W2 = Wv[(rz*3+dy)*3+2];
                    a00 = fmaf(v0, W0, fmaf(v1, W1, fmaf(v2, W2, a00)));
                    a01 = fmaf(v1, W0, fmaf(v2, W1, fmaf(v3, W2, a01)));
                    a02 = fmaf(v2, W0, fmaf(v3, W1, fmaf(v4, W2, a02)));
                    a03 = fmaf(v3, W0, fmaf(v4, W1, fmaf(v5, W2, a03)));
                }
                if (rz >= 1) {
                    const float W0 = Wv[((rz-1)*3+dy)*3], W1 = Wv[((rz-1)*3+dy)*3+1], W2 = Wv[((rz-1)*3+dy)*3+2];
                    a10 = fmaf(v0, W0, fmaf(v1, W1, fmaf(v2, W2, a10)));
                    a11 = fmaf(v1, W0, fmaf(v2, W1, fmaf(v3, W2, a11)));
                    a12 = fmaf(v2, W0, fmaf(v3, W1, fmaf(v4, W2, a12)));
                    a13 = fmaf(v3, W0, fmaf(v4, W1, fmaf(v5, W2, a13)));
                }
            }
        }
    };

    float4 Ma[12], Mb[12];
    LOADCH(0, Ma);
    for (int c = 0; c < Cc; c += 2) {
        LOADCH(c + 1, Mb);                 // prefetch while computing c
        COMPUTECH(c, Ma);
        if (c + 2 < Cc) LOADCH(c + 2, Ma); // prefetch while computing c+1
        COMPUTECH(c + 1, Mb);
    }

    // fuzzy + store (raw, into padded layout) + bn1 stats
    float fsum = 0.f, fsq = 0.f;
#pragma unroll
    for (int oz = 0; oz < 2; oz++) {
        float xv[4] = { oz ? a10 : a00, oz ? a11 : a01,
                        oz ? a12 : a02, oz ? a13 : a03 };
        float* fp = fuzz + (size_t)b * PSP + (size_t)(z0 + oz + 1) * PZR
                  + (y + 1) * PW + (w0 + 1);
#pragma unroll
        for (int ow = 0; ow < 4; ow++) {
            float x1 = xv[ow];
            float tt = x1 * x1 * S1 - 2.0f * x1 * S2 + S3;
            float fz = __expf(-tt);
            fp[ow] = fz; fsum += fz; fsq += fz * fz;
        }
    }
#pragma unroll
    for (int m = 1; m < 64; m <<= 1) {
        fsum += __shfl_xor(fsum, m, 64);
        fsq  += __shfl_xor(fsq,  m, 64);
    }
    __shared__ float red[8];
    const int wid = tid >> 6;
    if ((tid & 63) == 0) { red[wid * 2] = fsum; red[wid * 2 + 1] = fsq; }
    __syncthreads();
    if (tid == 0) {
        atomicAdd(&acc[0], red[0] + red[2] + red[4] + red[6]);
        atomicAdd(&acc[1], red[1] + red[3] + red[5] + red[7]);
    }
}

// ---------------- Kernel 2: finalize bn1 -> affine (a, c)
__global__ void k_fin1(const float* __restrict__ g, const float* __restrict__ be,
                       float* __restrict__ acc)
{
    float mean = acc[0] * (1.0f / TS);
    float var  = acc[1] * (1.0f / TS) - mean * mean;
    float a = g[0] * rsqrtf(var + 1e-5f);
    acc[2] = a;
    acc[3] = be[0] - mean * a;
}

// ---------------- Kernel 2b: apply bn1 affine in place over padded fuzz;
// write exact 0 into the pad ring (so conv2 needs no predication at all).
__global__ __launch_bounds__(256) void k_bn1_apply(
    float* __restrict__ fuzz, const float* __restrict__ acc)
{
    const int t = blockIdx.x * 256 + threadIdx.x;
    if (t >= PTOT) return;
    const int b  = t / PSP;  const int r  = t - b * PSP;
    const int zp = r / PZR;  const int r2 = r - zp * PZR;
    const int yp = r2 / PW;  const int wp = r2 - yp * PW;
    const bool inter = ((unsigned)(zp - 1) < 64u) &&
                       ((unsigned)(yp - 1) < 64u) &&
                       ((unsigned)(wp - 1) < 64u);
    const float a = acc[2], sh = acc[3];
    const float v = fuzz[t];
    fuzz[t] = inter ? fmaf(a, v, sh) : 0.f;
}

// ---------------- Kernel 3: conv2 single pass — RAW y to out + bn2 stats.
// Padded pre-affined fuzz -> 54 unconditional coalesced loads, no shuffles,
// no selects. Each of the 4 waves owns 8 channels; slot atomics for stats.
__global__ __launch_bounds__(256) void k_conv2_fused(
    const float* __restrict__ fuzz, const float* __restrict__ w2,
    const float* __restrict__ b2, float* __restrict__ acc,
    float* __restrict__ out)
{
    const int tid = threadIdx.x;
    const int lane = tid & 63;
    const int wid = tid >> 6;              // channel group 0..3
    const int bi = blockIdx.x;             // 4096 spatial tiles
    const int w = lane;
    const int y = bi & 63;
    const int z0 = ((bi >> 6) & 15) << 2;
    const int b = bi >> 10;
    const float* fb = fuzz + (size_t)b * PSP;

    float Fl[6][3], Fm[6][3], Fr[6][3];
#pragma unroll
    for (int rz = 0; rz < 6; rz++) {
#pragma unroll
        for (int dy = 0; dy < 3; dy++) {
            const float* rp = fb + (size_t)(z0 + rz) * PZR + (y + dy) * PW + w;
            Fl[rz][dy] = rp[0];
            Fm[rz][dy] = rp[1];
            Fr[rz][dy] = rp[2];
        }
    }

    float* ob = out + (size_t)b * Cc * SP + (z0 << 12) + (y << 6) + w;
    const int slot = bi & 63;
    const int c0 = wid * 8;

#pragma unroll
    for (int ci = 0; ci < 8; ci++) {
        const int c = c0 + ci;
        const float* wc = w2 + c * 27;     // uniform -> s_load
        float Wv[27];
#pragma unroll
        for (int k = 0; k < 27; k++) Wv[k] = wc[k];
        const float bb = b2[c];
        float o0 = bb, o1 = bb, o2 = bb, o3 = bb;
#pragma unroll
        for (int rz = 0; rz < 6; rz++) {
#pragma unroll
            for (int dy = 0; dy < 3; dy++) {
                const float l = Fl[rz][dy], m = Fm[rz][dy], r = Fr[rz][dy];
#pragma unroll
                for (int oz = 0; oz < 4; oz++) {
                    const int dz = rz - oz;
                    if (dz < 0 || dz > 2) continue;
                    const float W0 = Wv[(dz*3+dy)*3], W1 = Wv[(dz*3+dy)*3+1], W2 = Wv[(dz*3+dy)*3+2];
                    if      (oz == 0) o0 = fmaf(l, W0, fmaf(m, W1, fmaf(r, W2, o0)));
                    else if (oz == 1) o1 = fmaf(l, W0, fmaf(m, W1, fmaf(r, W2, o1)));
                    else if (oz == 2) o2 = fmaf(l, W0, fmaf(m, W1, fmaf(r, W2, o2)));
                    else              o3 = fmaf(l, W0, fmaf(m, W1, fmaf(r, W2, o3)));
                }
            }
        }
        // write raw y (coalesced 256B per store)
        ob[(size_t)c * SP]         = o0;
        ob[(size_t)c * SP + 4096]  = o1;
        ob[(size_t)c * SP + 8192]  = o2;
        ob[(size_t)c * SP + 12288] = o3;

        float ps = (o0 + o1) + (o2 + o3);
        float pq = fmaf(o0, o0, fmaf(o1, o1, fmaf(o2, o2, o3 * o3)));
#pragma unroll
        for (int mm = 1; mm < 64; mm <<= 1) {
            ps += __shfl_xor(ps, mm, 64);
            pq += __shfl_xor(pq, mm, 64);
        }
        if (lane == 0) {
            atomicAdd(&acc[68 + c * 64 + slot], ps);
            atomicAdd(&acc[68 + (32 + c) * 64 + slot], pq);
        }
    }
}

// ---------------- Kernel 4: finalize bn2 -> per-channel scale/shift
__global__ void k_fin2(const float* __restrict__ g, const float* __restrict__ be,
                       float* __restrict__ acc)
{
    int c = threadIdx.x;                  // 32 threads
    float s = 0.f, q = 0.f;
    for (int k = 0; k < 64; k++) {
        s += acc[68 + c * 64 + k];
        q += acc[68 + (32 + c) * 64 + k];
    }
    float mean = s * (1.0f / TS);
    float var  = q * (1.0f / TS) - mean * mean;
    float sc = g[c] * rsqrtf(var + 1e-5f);
    acc[4 + c]  = sc;
    acc[36 + c] = be[c] - mean * sc;
}

// ---------------- Kernel 5: bn2 affine applied in place (float4 streaming)
__global__ __launch_bounds__(256) void k_bn2_apply(
    const float* __restrict__ acc, float* __restrict__ out)
{
    const int t = blockIdx.x * 256 + threadIdx.x;   // 8388608 threads
    const int c = (t >> 16) & 31;                   // SP/4 = 65536 float4 per (b,c)
    const float sc = acc[4 + c], sh = acc[36 + c];
    float4 v = ((const float4*)out)[t];
    v.x = fmaf(v.x, sc, sh);
    v.y = fmaf(v.y, sc, sh);
    v.z = fmaf(v.z, sc, sh);
    v.w = fmaf(v.w, sc, sh);
    ((float4*)out)[t] = v;
}

extern "C" void kernel_launch(void* const* d_in, const int* in_sizes, int n_in,
                              void* d_out, int out_size, void* d_ws, size_t ws_size,
                              hipStream_t stream)
{
    const float* x   = (const float*)d_in[0];
    const float* w1  = (const float*)d_in[1];
    const float* b1  = (const float*)d_in[2];
    const float* w2  = (const float*)d_in[3];
    const float* b2  = (const float*)d_in[4];
    const float* mu  = (const float*)d_in[5];
    const float* sg  = (const float*)d_in[6];
    const float* g1  = (const float*)d_in[7];
    const float* be1 = (const float*)d_in[8];
    const float* g2  = (const float*)d_in[9];
    const float* be2 = (const float*)d_in[10];

    float* out  = (float*)d_out;
    float* fuzz = (float*)d_ws;
    float* acc  = fuzz + PTOT;

    hipMemsetAsync(acc, 0, ACC_N * sizeof(float), stream);
    k_conv1_fuzzy<<<512, 256, 0, stream>>>(x, w1, b1, mu, sg, fuzz, acc);
    k_fin1<<<1, 1, 0, stream>>>(g1, be1, acc);
    k_bn1_apply<<<(PTOT + 255) / 256, 256, 0, stream>>>(fuzz, acc);
    k_conv2_fused<<<4096, 256, 0, stream>>>(fuzz, w2, b2, acc, out);
    k_fin2<<<1, 32, 0, stream>>>(g2, be2, acc);
    k_bn2_apply<<<32768, 256, 0, stream>>>(acc, out);
}